// Round 5
// baseline (4815.779 us; speedup 1.0000x reference)
//
#include <hip/hip_runtime.h>

// Problem constants
#define BS   1024        // B*S rows
#define DD   1024        // D
#define VV   32000       // V
#define TOPK 50
#define TOPPF 0.95f
#define NVTOT 32768000ull   // BS*VV

// ---------------------------------------------------------------- utilities
__device__ __forceinline__ unsigned fkey(float f) {
  unsigned u = __float_as_uint(f);
  return (u & 0x80000000u) ? ~u : (u | 0x80000000u);
}
__device__ __forceinline__ float fkeyinv(unsigned k) {
  unsigned u = (k & 0x80000000u) ? (k & 0x7FFFFFFFu) : ~k;
  return __uint_as_float(u);
}
__device__ __forceinline__ unsigned rotl32(unsigned x, int r) {
  return (x << r) | (x >> (32 - r));
}

// JAX threefry2x32-20, key = (0, 42), partitionable mode:
// counter = (hi32, lo32) of 64-bit flat index = (0, i)  [iota_2x32_shape];
// for bit_width 32 JAX returns bits1 ^ bits2 (XOR of BOTH output words),
// NOT a truncation of the 64-bit block.
__device__ float gumbel_at(unsigned i) {
  unsigned x0 = 0u, x1 = i;
  const unsigned ks0 = 0u, ks1 = 42u, ks2 = 0x1BD11BDAu ^ 0u ^ 42u;
  x0 += ks0; x1 += ks1;
  const int rotA[4] = {13, 15, 26, 6};
  const int rotB[4] = {17, 29, 16, 24};
#define TF_R4(R) { x0 += x1; x1 = rotl32(x1, R[0]); x1 ^= x0; \
                   x0 += x1; x1 = rotl32(x1, R[1]); x1 ^= x0; \
                   x0 += x1; x1 = rotl32(x1, R[2]); x1 ^= x0; \
                   x0 += x1; x1 = rotl32(x1, R[3]); x1 ^= x0; }
  TF_R4(rotA); x0 += ks1; x1 += ks2 + 1u;
  TF_R4(rotB); x0 += ks2; x1 += ks0 + 2u;
  TF_R4(rotA); x0 += ks0; x1 += ks1 + 3u;
  TF_R4(rotB); x0 += ks1; x1 += ks2 + 4u;
  TF_R4(rotA); x0 += ks2; x1 += ks0 + 5u;
#undef TF_R4
  unsigned bits = x0 ^ x1;   // partitionable 32-bit path: XOR-fold of both words
  float f = __uint_as_float(0x3F800000u | (bits >> 9)) - 1.0f;
  float u = fmaxf(f, 1.17549435e-38f);   // uniform(minval=tiny, maxval=1)
  return -logf(-logf(u));
}

// ---------------------------------------------------------------- GEMM
// amp_sq[m][v] = |psi[m] . proj W[v]|^2  via 4 real dot products.
// tile 64x64, BK=16, 256 threads, 4x4 outputs/thread, fp32.
__global__ __launch_bounds__(256) void gemm_amp(
    const float* __restrict__ pr, const float* __restrict__ pi,
    const float* __restrict__ wr, const float* __restrict__ wi,
    float* __restrict__ amp) {
  __shared__ __align__(16) float Ar[16][64];
  __shared__ __align__(16) float Ai[16][64];
  __shared__ __align__(16) float Br[16][64];
  __shared__ __align__(16) float Bi[16][64];

  const int bn = blockIdx.x;        // 0..499  (V tiles)
  const int bm = blockIdx.y;        // 0..15   (row tiles)
  const int tid = threadIdx.x;
  const int ty = tid >> 4, tx = tid & 15;
  const int row0 = bm * 64, col0 = bn * 64;
  const int lrow = tid >> 2;        // 0..63
  const int lk4  = (tid & 3) * 4;   // 0,4,8,12

  const float* pA_r = pr + (size_t)(row0 + lrow) * DD + lk4;
  const float* pA_i = pi + (size_t)(row0 + lrow) * DD + lk4;
  const float* pB_r = wr + (size_t)(col0 + lrow) * DD + lk4;
  const float* pB_i = wi + (size_t)(col0 + lrow) * DD + lk4;

  float accr[4][4] = {}, acci[4][4] = {};

  for (int k0 = 0; k0 < DD; k0 += 16) {
    float4 ar = *(const float4*)(pA_r + k0);
    float4 ai = *(const float4*)(pA_i + k0);
    float4 br = *(const float4*)(pB_r + k0);
    float4 bi = *(const float4*)(pB_i + k0);
    __syncthreads();
    Ar[lk4 + 0][lrow] = ar.x; Ar[lk4 + 1][lrow] = ar.y;
    Ar[lk4 + 2][lrow] = ar.z; Ar[lk4 + 3][lrow] = ar.w;
    Ai[lk4 + 0][lrow] = ai.x; Ai[lk4 + 1][lrow] = ai.y;
    Ai[lk4 + 2][lrow] = ai.z; Ai[lk4 + 3][lrow] = ai.w;
    Br[lk4 + 0][lrow] = br.x; Br[lk4 + 1][lrow] = br.y;
    Br[lk4 + 2][lrow] = br.z; Br[lk4 + 3][lrow] = br.w;
    Bi[lk4 + 0][lrow] = bi.x; Bi[lk4 + 1][lrow] = bi.y;
    Bi[lk4 + 2][lrow] = bi.z; Bi[lk4 + 3][lrow] = bi.w;
    __syncthreads();
#pragma unroll
    for (int k = 0; k < 16; ++k) {
      float a_r[4], a_i[4], b_r[4], b_i[4];
      float4 t;
      t = *(const float4*)&Ar[k][ty * 4]; a_r[0]=t.x; a_r[1]=t.y; a_r[2]=t.z; a_r[3]=t.w;
      t = *(const float4*)&Ai[k][ty * 4]; a_i[0]=t.x; a_i[1]=t.y; a_i[2]=t.z; a_i[3]=t.w;
      t = *(const float4*)&Br[k][tx * 4]; b_r[0]=t.x; b_r[1]=t.y; b_r[2]=t.z; b_r[3]=t.w;
      t = *(const float4*)&Bi[k][tx * 4]; b_i[0]=t.x; b_i[1]=t.y; b_i[2]=t.z; b_i[3]=t.w;
#pragma unroll
      for (int i = 0; i < 4; ++i)
#pragma unroll
        for (int j = 0; j < 4; ++j) {
          accr[i][j] += a_r[i] * b_r[j] - a_i[i] * b_i[j];
          acci[i][j] += a_i[i] * b_r[j] + a_r[i] * b_i[j];
        }
    }
  }
#pragma unroll
  for (int i = 0; i < 4; ++i) {
    float4 o;
    o.x = accr[i][0]*accr[i][0] + acci[i][0]*acci[i][0];
    o.y = accr[i][1]*accr[i][1] + acci[i][1]*acci[i][1];
    o.z = accr[i][2]*accr[i][2] + acci[i][2]*acci[i][2];
    o.w = accr[i][3]*accr[i][3] + acci[i][3]*acci[i][3];
    *(float4*)&amp[(size_t)(row0 + ty * 4 + i) * VV + col0 + tx * 4] = o;
  }
}

// ------------------------------------------------- per-row logits/logsoftmax
__global__ __launch_bounds__(256) void row_logits(
    const float* __restrict__ amp, const float* __restrict__ bias,
    float* __restrict__ logits, float* __restrict__ logprobs) {
  const int row = blockIdx.x, tid = threadIdx.x;
  const float* A = amp + (size_t)row * VV;
  float* Lg = logits + (size_t)row * VV;
  float* Lp = logprobs + (size_t)row * VV;
  __shared__ float red[256];

  float s = 0.f;
  for (int v = tid; v < VV; v += 256) s += A[v];
  red[tid] = s; __syncthreads();
  for (int o = 128; o > 0; o >>= 1) { if (tid < o) red[tid] += red[tid + o]; __syncthreads(); }
  const float floorv = red[0] * (1.0f / (float)VV) * 1e-6f + 1e-30f;
  __syncthreads();

  float mx = -INFINITY;
  for (int v = tid; v < VV; v += 256) {
    float l = logf(A[v] + floorv) + bias[v];   // TEMP == 1.0 -> no-op divide
    Lg[v] = l;
    mx = fmaxf(mx, l);
  }
  red[tid] = mx; __syncthreads();
  for (int o = 128; o > 0; o >>= 1) { if (tid < o) red[tid] = fmaxf(red[tid], red[tid + o]); __syncthreads(); }
  mx = red[0]; __syncthreads();

  float se = 0.f;
  for (int v = tid; v < VV; v += 256) se += expf(Lg[v] - mx);
  red[tid] = se; __syncthreads();
  for (int o = 128; o > 0; o >>= 1) { if (tid < o) red[tid] += red[tid + o]; __syncthreads(); }
  const float lse = mx + logf(red[0]);

  for (int v = tid; v < VV; v += 256) Lp[v] = Lg[v] - lse;
}

// ------------------------------------------------- top-k radix select (kth)
__global__ __launch_bounds__(256) void topk_sel(
    const float* __restrict__ logits, float* __restrict__ ws_kth) {
  const int row = blockIdx.x, tid = threadIdx.x;
  const float* L = logits + (size_t)row * VV;
  __shared__ int hist[256];
  __shared__ unsigned sh_bin;
  __shared__ int sh_kk;

  unsigned pmask = 0u, pval = 0u;
  int kk = TOPK;
  for (int pass = 0; pass < 4; ++pass) {
    const int shift = 24 - 8 * pass;
    if (tid < 256) hist[tid] = 0;
    __syncthreads();
    for (int v = tid; v < VV; v += 256) {
      unsigned u = fkey(L[v]);
      if ((u & pmask) == pval) atomicAdd(&hist[(u >> shift) & 255u], 1);
    }
    __syncthreads();
    if (tid == 0) {
      int c = 0, b = 255;
      for (; b >= 0; --b) {
        if (c + hist[b] >= kk) break;
        c += hist[b];
      }
      sh_bin = (unsigned)b; sh_kk = kk - c;
    }
    __syncthreads();
    pval |= (sh_bin << shift);
    pmask |= (0xFFu << shift);
    kk = sh_kk;
    __syncthreads();
  }
  if (tid == 0) ws_kth[row] = fkeyinv(pval);
}

// ------------------------------------------------- top-p boundary per row
__global__ __launch_bounds__(256) void topp_sel(
    const float* __restrict__ logits, const float* __restrict__ ws_kth,
    float* __restrict__ ws_vb, int* __restrict__ ws_ib,
    float* __restrict__ ws_mx, float* __restrict__ ws_dk) {
  const int row = blockIdx.x, tid = threadIdx.x;
  const float* L = logits + (size_t)row * VV;
  const float kth = ws_kth[row];
  __shared__ float sval[512]; __shared__ int sidx[512];
  __shared__ float ssv[512];  __shared__ int ssi[512];
  __shared__ int scnt;
  if (tid == 0) scnt = 0;
  __syncthreads();
  for (int v = tid; v < VV; v += 256) {
    float l = L[v];
    if (l >= kth) {
      int p = atomicAdd(&scnt, 1);
      if (p < 512) { sval[p] = l; sidx[p] = v; }
    }
  }
  __syncthreads();
  const int n = min(scnt, 512);
  // rank sort: value desc, index asc (matches stable argsort(-filt))
  for (int i = tid; i < n; i += 256) {
    float vi = sval[i]; int ii = sidx[i]; int r = 0;
    for (int j = 0; j < n; ++j) {
      float vj = sval[j]; int ij = sidx[j];
      r += (vj > vi) || (vj == vi && ij < ii);
    }
    ssv[r] = vi; ssi[r] = ii;
  }
  __syncthreads();
  if (tid == 0) {
    const float mx = ssv[0];
    float denom = 0.f;
    for (int j = 0; j < n; ++j) denom += expf(ssv[j] - mx);
    float cum = 0.f; int m = n;
    for (int j = 0; j < n; ++j) {
      float sp = expf(ssv[j] - mx) / denom;
      cum += sp;
      if (cum - sp >= TOPPF) { m = j; break; }   // replicate (cum - sp) >= TOP_P
    }
    float dk = 0.f;
    for (int j = 0; j < m; ++j) dk += expf(ssv[j] - mx);
    ws_vb[row] = ssv[m - 1];
    ws_ib[row] = ssi[m - 1];
    ws_mx[row] = mx;
    ws_dk[row] = dk;
  }
}

// ------------------------------------------------- probs + gumbel argmax
__global__ __launch_bounds__(256) void probs_tokens(
    const float* __restrict__ logits,
    const float* __restrict__ ws_vb, const int* __restrict__ ws_ib,
    const float* __restrict__ ws_mx, const float* __restrict__ ws_dk,
    float* __restrict__ probs, float* __restrict__ tokens) {
  const int row = blockIdx.x, tid = threadIdx.x;
  const float* Lg = logits + (size_t)row * VV;
  float* P = probs + (size_t)row * VV;
  const float vb = ws_vb[row]; const int ib = ws_ib[row];
  const float mx = ws_mx[row]; const float dk = ws_dk[row];

  float best = -INFINITY; int bidx = 0x7FFFFFFF;
  for (int v = tid; v < VV; v += 256) {
    float l = Lg[v];
    bool kept = (l > vb) || (l == vb && v <= ib);
    float p = 0.f;
    if (kept) {
      p = expf(l - mx) / dk;
      float g = gumbel_at((unsigned)(row * VV + v));
      float sc = l + g;
      if (sc > best || (sc == best && v < bidx)) { best = sc; bidx = v; }
    }
    P[v] = p;
  }
  __shared__ float bv[256]; __shared__ int bi[256];
  bv[tid] = best; bi[tid] = bidx; __syncthreads();
  for (int o = 128; o > 0; o >>= 1) {
    if (tid < o) {
      if (bv[tid + o] > bv[tid] ||
          (bv[tid + o] == bv[tid] && bi[tid + o] < bi[tid])) {
        bv[tid] = bv[tid + o]; bi[tid] = bi[tid + o];
      }
    }
    __syncthreads();
  }
  if (tid == 0) tokens[row] = (float)bi[0];
}

// ---------------------------------------------------------------- launcher
extern "C" void kernel_launch(void* const* d_in, const int* in_sizes, int n_in,
                              void* d_out, int out_size, void* d_ws, size_t ws_size,
                              hipStream_t stream) {
  const float* pr   = (const float*)d_in[0];
  const float* pi   = (const float*)d_in[1];
  const float* wr   = (const float*)d_in[2];
  const float* wi   = (const float*)d_in[3];
  const float* bias = (const float*)d_in[4];

  float* out      = (float*)d_out;
  float* logits   = out;                       // [1024, 32000]
  float* logprobs = out + NVTOT;               // [1024, 32000]
  float* ampsq    = out + 2 * NVTOT;           // [1024, 32000]
  float* tokens   = out + 3 * NVTOT;           // [1024]
  float* probs    = out + 3 * NVTOT + 1024;    // [1024, 32000]

  float* ws     = (float*)d_ws;
  float* ws_kth = ws;                // 1024
  float* ws_vb  = ws + 1024;         // 1024
  int*   ws_ib  = (int*)(ws + 2048); // 1024
  float* ws_mx  = ws + 3072;         // 1024
  float* ws_dk  = ws + 4096;         // 1024

  dim3 gemm_grid(VV / 64, BS / 64);
  gemm_amp<<<gemm_grid, 256, 0, stream>>>(pr, pi, wr, wi, ampsq);
  row_logits<<<BS, 256, 0, stream>>>(ampsq, bias, logits, logprobs);
  topk_sel<<<BS, 256, 0, stream>>>(logits, ws_kth);
  topp_sel<<<BS, 256, 0, stream>>>(logits, ws_kth, ws_vb, ws_ib, ws_mx, ws_dk);
  probs_tokens<<<BS, 256, 0, stream>>>(logits, ws_vb, ws_ib, ws_mx, ws_dk, probs, tokens);
}

// Round 6
// 1422.240 us; speedup vs baseline: 3.3861x; 3.3861x over previous
//
#include <hip/hip_runtime.h>

// Problem constants
#define BS   1024        // B*S rows
#define DD   1024        // D (= K)
#define VV   32000       // V
#define TOPK 50
#define TOPPF 0.95f
#define NVTOT 32768000ull   // BS*VV

typedef __attribute__((ext_vector_type(8))) short bf16x8;
typedef __attribute__((ext_vector_type(4))) float f32x4;
typedef __attribute__((ext_vector_type(4))) int   i32x4;

#define MFMA(A,B,C) __builtin_amdgcn_mfma_f32_16x16x32_bf16(A, B, C, 0, 0, 0)

// ---------------------------------------------------------------- utilities
__device__ __forceinline__ unsigned fkey(float f) {
  unsigned u = __float_as_uint(f);
  return (u & 0x80000000u) ? ~u : (u | 0x80000000u);
}
__device__ __forceinline__ float fkeyinv(unsigned k) {
  unsigned u = (k & 0x80000000u) ? (k & 0x7FFFFFFFu) : ~k;
  return __uint_as_float(u);
}
__device__ __forceinline__ unsigned rotl32(unsigned x, int r) {
  return (x << r) | (x >> (32 - r));
}
__device__ __forceinline__ ushort f2bf(float f) {   // fp32 -> bf16 RNE
  unsigned u = __float_as_uint(f);
  unsigned r = ((u >> 16) & 1u) + 0x7FFFu;
  return (ushort)((u + r) >> 16);
}
__device__ __forceinline__ float bf2f(ushort h) {
  return __uint_as_float(((unsigned)h) << 16);
}
__device__ __forceinline__ bf16x8 negbf(bf16x8 a) {  // flip sign of 8 bf16
  i32x4 t = __builtin_bit_cast(i32x4, a);
  t = t ^ 0x80008000;
  return __builtin_bit_cast(bf16x8, t);
}

// JAX threefry2x32-20, key=(0,42), partitionable: counter (0, i), bits = w0^w1.
__device__ float gumbel_at(unsigned i) {
  unsigned x0 = 0u, x1 = i;
  const unsigned ks0 = 0u, ks1 = 42u, ks2 = 0x1BD11BDAu ^ 0u ^ 42u;
  x0 += ks0; x1 += ks1;
  const int rotA[4] = {13, 15, 26, 6};
  const int rotB[4] = {17, 29, 16, 24};
#define TF_R4(R) { x0 += x1; x1 = rotl32(x1, R[0]); x1 ^= x0; \
                   x0 += x1; x1 = rotl32(x1, R[1]); x1 ^= x0; \
                   x0 += x1; x1 = rotl32(x1, R[2]); x1 ^= x0; \
                   x0 += x1; x1 = rotl32(x1, R[3]); x1 ^= x0; }
  TF_R4(rotA); x0 += ks1; x1 += ks2 + 1u;
  TF_R4(rotB); x0 += ks2; x1 += ks0 + 2u;
  TF_R4(rotA); x0 += ks0; x1 += ks1 + 3u;
  TF_R4(rotB); x0 += ks1; x1 += ks2 + 4u;
  TF_R4(rotA); x0 += ks2; x1 += ks0 + 5u;
#undef TF_R4
  unsigned bits = x0 ^ x1;
  float f = __uint_as_float(0x3F800000u | (bits >> 9)) - 1.0f;
  float u = fmaxf(f, 1.17549435e-38f);
  return -logf(-logf(u));
}

// ------------------------------------------------- split fp32 -> bf16 hi/lo
// imag component scaled by si (psi: si=-1 stores negated imag; W: si=+1).
__global__ __launch_bounds__(256) void pack_split(
    const float* __restrict__ xr, const float* __restrict__ xi,
    ushort* __restrict__ ohr, ushort* __restrict__ olr,
    ushort* __restrict__ ohi, ushort* __restrict__ oli,
    float si, int n4) {
  int g = blockIdx.x * 256 + threadIdx.x;
  if (g >= n4) return;
  int i = g * 4;
  float4 a = *(const float4*)(xr + i);
  float4 b = *(const float4*)(xi + i);
  float av[4] = {a.x, a.y, a.z, a.w};
  float bv[4] = {b.x * si, b.y * si, b.z * si, b.w * si};
  unsigned hr[4], lr[4], hi_[4], li[4];
#pragma unroll
  for (int j = 0; j < 4; ++j) {
    ushort h = f2bf(av[j]);          hr[j] = h;
    lr[j] = f2bf(av[j] - bf2f(h));
    ushort h2 = f2bf(bv[j]);         hi_[j] = h2;
    li[j] = f2bf(bv[j] - bf2f(h2));
  }
  uint2 w;
  w.x = hr[0] | (hr[1] << 16); w.y = hr[2] | (hr[3] << 16);
  *(uint2*)(ohr + i) = w;
  w.x = lr[0] | (lr[1] << 16); w.y = lr[2] | (lr[3] << 16);
  *(uint2*)(olr + i) = w;
  w.x = hi_[0] | (hi_[1] << 16); w.y = hi_[2] | (hi_[3] << 16);
  *(uint2*)(ohi + i) = w;
  w.x = li[0] | (li[1] << 16); w.y = li[2] | (li[3] << 16);
  *(uint2*)(oli + i) = w;
}

// ---------------------------------------------------------------- MFMA GEMM
// amp_sq = |(Pr + iPi) . (Wr + iWi)|^2, split-bf16 (3-term), 12 MFMA/frag-pair.
// Block 128x128, 8 waves (2x4), wave tile 64x32, BK=64.
// LDS tiles XOR-swizzled (byte ^= (row&7)<<4) via inverse-swizzled gload src.
__global__ __launch_bounds__(512, 2) void gemm_mfma(
    const ushort* __restrict__ APk,                      // [4][1024][1024]
    const ushort* __restrict__ Wrh, const ushort* __restrict__ Wrl,
    const ushort* __restrict__ Wih, const ushort* __restrict__ Wil,
    float* __restrict__ amp) {
  __shared__ ushort lds[8][8192];    // 8 tiles x 16KB = 128KB
  const int tid = threadIdx.x;
  const int lane = tid & 63, wid = tid >> 6;
  const int bm = blockIdx.x & 7, bn = blockIdx.x >> 3;
  const int row0 = bm << 7, col0 = bn << 7;
  const int wm = wid >> 2, wn = wid & 3;     // wave grid 2(M) x 4(N)

  const ushort* tp[8] = {APk, APk + (1 << 20), APk + (2 << 20), APk + (3 << 20),
                         Wrh, Wrl, Wih, Wil};
  const int tb[8] = {row0, row0, row0, row0, col0, col0, col0, col0};

  f32x4 accr[4][2] = {}, acci[4][2] = {};

  for (int step = 0; step < 16; ++step) {
    const int k0 = step << 6;
    if (step) __syncthreads();      // previous compute done
#pragma unroll
    for (int t = 0; t < 8; ++t) {
#pragma unroll
      for (int r = 0; r < 2; ++r) {
        const int seg = wid + (r << 3);          // 0..15 wave segments
        const int c = (seg << 6) + lane;         // 16B chunk id, 0..1023
        const int rrow = c >> 3;                 // tile row 0..127
        const int ss = (c & 7) ^ (rrow & 7);     // inverse-swizzled k-slot
        const ushort* src = tp[t] + (size_t)(tb[t] + rrow) * DD + k0 + (ss << 3);
        __builtin_amdgcn_global_load_lds(
            (const __attribute__((address_space(1))) unsigned int*)src,
            (__attribute__((address_space(3))) unsigned int*)&lds[t][seg << 9],
            16, 0, 0);
      }
    }
    __syncthreads();                // staged (vmcnt drained by compiler)
#pragma unroll
    for (int s = 0; s < 2; ++s) {
      const int kb = (s << 6) + ((lane >> 4) << 4);
      bf16x8 aPrh[4], aPrl[4], aNih[4], aNil[4], aPih[4], aPil[4];
#pragma unroll
      for (int m = 0; m < 4; ++m) {
        const int ar = (wm << 6) + (m << 4) + (lane & 15);
        const int off = (ar << 7) + (kb ^ ((ar & 7) << 4));
        aPrh[m] = *(const bf16x8*)((const char*)&lds[0][0] + off);
        aPrl[m] = *(const bf16x8*)((const char*)&lds[1][0] + off);
        aNih[m] = *(const bf16x8*)((const char*)&lds[2][0] + off);
        aNil[m] = *(const bf16x8*)((const char*)&lds[3][0] + off);
        aPih[m] = negbf(aNih[m]);
        aPil[m] = negbf(aNil[m]);
      }
#pragma unroll
      for (int n = 0; n < 2; ++n) {
        const int br = (wn << 5) + (n << 4) + (lane & 15);
        const int off = (br << 7) + (kb ^ ((br & 7) << 4));
        bf16x8 bRh = *(const bf16x8*)((const char*)&lds[4][0] + off);
        bf16x8 bRl = *(const bf16x8*)((const char*)&lds[5][0] + off);
        bf16x8 bIh = *(const bf16x8*)((const char*)&lds[6][0] + off);
        bf16x8 bIl = *(const bf16x8*)((const char*)&lds[7][0] + off);
#pragma unroll
        for (int m = 0; m < 4; ++m) {
          f32x4 r = accr[m][n], q = acci[m][n];
          r = MFMA(aPrh[m], bRh, r); r = MFMA(aPrh[m], bRl, r); r = MFMA(aPrl[m], bRh, r);
          r = MFMA(aNih[m], bIh, r); r = MFMA(aNih[m], bIl, r); r = MFMA(aNil[m], bIh, r);
          q = MFMA(aPih[m], bRh, q); q = MFMA(aPih[m], bRl, q); q = MFMA(aPil[m], bRh, q);
          q = MFMA(aPrh[m], bIh, q); q = MFMA(aPrh[m], bIl, q); q = MFMA(aPrl[m], bIh, q);
          accr[m][n] = r; acci[m][n] = q;
        }
      }
    }
  }
  // epilogue: C/D mapping col=lane&15, row=(lane>>4)*4+reg
#pragma unroll
  for (int m = 0; m < 4; ++m)
#pragma unroll
    for (int n = 0; n < 2; ++n)
#pragma unroll
      for (int qi = 0; qi < 4; ++qi) {
        const int row = row0 + (wm << 6) + (m << 4) + ((lane >> 4) << 2) + qi;
        const int col = col0 + (wn << 5) + (n << 4) + (lane & 15);
        float vr = accr[m][n][qi], vi = acci[m][n][qi];
        amp[(size_t)row * VV + col] = vr * vr + vi * vi;
      }
}

// ------------------------------------------------- per-row logits/logsoftmax
__global__ __launch_bounds__(256) void row_logits(
    const float* __restrict__ amp, const float* __restrict__ bias,
    float* __restrict__ logits, float* __restrict__ logprobs) {
  const int row = blockIdx.x, tid = threadIdx.x;
  const float* A = amp + (size_t)row * VV;
  float* Lg = logits + (size_t)row * VV;
  float* Lp = logprobs + (size_t)row * VV;
  __shared__ float red[256];

  float s = 0.f;
  for (int v = tid; v < VV; v += 256) s += A[v];
  red[tid] = s; __syncthreads();
  for (int o = 128; o > 0; o >>= 1) { if (tid < o) red[tid] += red[tid + o]; __syncthreads(); }
  const float floorv = red[0] * (1.0f / (float)VV) * 1e-6f + 1e-30f;
  __syncthreads();

  float mx = -INFINITY;
  for (int v = tid; v < VV; v += 256) {
    float l = logf(A[v] + floorv) + bias[v];
    Lg[v] = l;
    mx = fmaxf(mx, l);
  }
  red[tid] = mx; __syncthreads();
  for (int o = 128; o > 0; o >>= 1) { if (tid < o) red[tid] = fmaxf(red[tid], red[tid + o]); __syncthreads(); }
  mx = red[0]; __syncthreads();

  float se = 0.f;
  for (int v = tid; v < VV; v += 256) se += expf(Lg[v] - mx);
  red[tid] = se; __syncthreads();
  for (int o = 128; o > 0; o >>= 1) { if (tid < o) red[tid] += red[tid + o]; __syncthreads(); }
  const float lse = mx + logf(red[0]);

  for (int v = tid; v < VV; v += 256) Lp[v] = Lg[v] - lse;
}

// ------------------------------------------------- top-k radix select (kth)
__global__ __launch_bounds__(256) void topk_sel(
    const float* __restrict__ logits, float* __restrict__ ws_kth) {
  const int row = blockIdx.x, tid = threadIdx.x;
  const float* L = logits + (size_t)row * VV;
  __shared__ int hist[256];
  __shared__ unsigned sh_bin;
  __shared__ int sh_kk;

  unsigned pmask = 0u, pval = 0u;
  int kk = TOPK;
  for (int pass = 0; pass < 4; ++pass) {
    const int shift = 24 - 8 * pass;
    hist[tid] = 0;
    __syncthreads();
    for (int v = tid; v < VV; v += 256) {
      unsigned u = fkey(L[v]);
      if ((u & pmask) == pval) atomicAdd(&hist[(u >> shift) & 255u], 1);
    }
    __syncthreads();
    if (tid == 0) {
      int c = 0, b = 255;
      for (; b >= 0; --b) {
        if (c + hist[b] >= kk) break;
        c += hist[b];
      }
      sh_bin = (unsigned)b; sh_kk = kk - c;
    }
    __syncthreads();
    pval |= (sh_bin << shift);
    pmask |= (0xFFu << shift);
    kk = sh_kk;
    __syncthreads();
  }
  if (tid == 0) ws_kth[row] = fkeyinv(pval);
}

// ------------------------------------------------- top-p boundary per row
__global__ __launch_bounds__(256) void topp_sel(
    const float* __restrict__ logits, const float* __restrict__ ws_kth,
    float* __restrict__ ws_vb, int* __restrict__ ws_ib,
    float* __restrict__ ws_mx, float* __restrict__ ws_dk) {
  const int row = blockIdx.x, tid = threadIdx.x;
  const float* L = logits + (size_t)row * VV;
  const float kth = ws_kth[row];
  __shared__ float sval[512]; __shared__ int sidx[512];
  __shared__ float ssv[512];  __shared__ int ssi[512];
  __shared__ int scnt;
  if (tid == 0) scnt = 0;
  __syncthreads();
  for (int v = tid; v < VV; v += 256) {
    float l = L[v];
    if (l >= kth) {
      int p = atomicAdd(&scnt, 1);
      if (p < 512) { sval[p] = l; sidx[p] = v; }
    }
  }
  __syncthreads();
  const int n = min(scnt, 512);
  for (int i = tid; i < n; i += 256) {
    float vi = sval[i]; int ii = sidx[i]; int r = 0;
    for (int j = 0; j < n; ++j) {
      float vj = sval[j]; int ij = sidx[j];
      r += (vj > vi) || (vj == vi && ij < ii);
    }
    ssv[r] = vi; ssi[r] = ii;
  }
  __syncthreads();
  if (tid == 0) {
    const float mx = ssv[0];
    float denom = 0.f;
    for (int j = 0; j < n; ++j) denom += expf(ssv[j] - mx);
    float cum = 0.f; int m = n;
    for (int j = 0; j < n; ++j) {
      float sp = expf(ssv[j] - mx) / denom;
      cum += sp;
      if (cum - sp >= TOPPF) { m = j; break; }
    }
    float dk = 0.f;
    for (int j = 0; j < m; ++j) dk += expf(ssv[j] - mx);
    ws_vb[row] = ssv[m - 1];
    ws_ib[row] = ssi[m - 1];
    ws_mx[row] = mx;
    ws_dk[row] = dk;
  }
}

// ------------------------------------------------- probs + gumbel argmax
__global__ __launch_bounds__(256) void probs_tokens(
    const float* __restrict__ logits,
    const float* __restrict__ ws_vb, const int* __restrict__ ws_ib,
    const float* __restrict__ ws_mx, const float* __restrict__ ws_dk,
    float* __restrict__ probs, float* __restrict__ tokens) {
  const int row = blockIdx.x, tid = threadIdx.x;
  const float* Lg = logits + (size_t)row * VV;
  float* P = probs + (size_t)row * VV;
  const float vb = ws_vb[row]; const int ib = ws_ib[row];
  const float mx = ws_mx[row]; const float dk = ws_dk[row];

  float best = -INFINITY; int bidx = 0x7FFFFFFF;
  for (int v = tid; v < VV; v += 256) {
    float l = Lg[v];
    bool kept = (l > vb) || (l == vb && v <= ib);
    float p = 0.f;
    if (kept) {
      p = expf(l - mx) / dk;
      float g = gumbel_at((unsigned)(row * VV + v));
      float sc = l + g;
      if (sc > best || (sc == best && v < bidx)) { best = sc; bidx = v; }
    }
    P[v] = p;
  }
  __shared__ float bv[256]; __shared__ int bi[256];
  bv[tid] = best; bi[tid] = bidx; __syncthreads();
  for (int o = 128; o > 0; o >>= 1) {
    if (tid < o) {
      if (bv[tid + o] > bv[tid] ||
          (bv[tid + o] == bv[tid] && bi[tid + o] < bi[tid])) {
        bv[tid] = bv[tid + o]; bi[tid] = bi[tid + o];
      }
    }
    __syncthreads();
  }
  if (tid == 0) tokens[row] = (float)bi[0];
}

// ---------------------------------------------------------------- launcher
extern "C" void kernel_launch(void* const* d_in, const int* in_sizes, int n_in,
                              void* d_out, int out_size, void* d_ws, size_t ws_size,
                              hipStream_t stream) {
  const float* pr   = (const float*)d_in[0];
  const float* pi   = (const float*)d_in[1];
  const float* wr   = (const float*)d_in[2];
  const float* wi   = (const float*)d_in[3];
  const float* bias = (const float*)d_in[4];

  float* out      = (float*)d_out;
  float* logits   = out;                       // [1024, 32000]
  float* logprobs = out + NVTOT;               // [1024, 32000]
  float* ampsq    = out + 2 * NVTOT;           // [1024, 32000]
  float* tokens   = out + 3 * NVTOT;           // [1024]
  float* probs    = out + 3 * NVTOT + 1024;    // [1024, 32000]

  // scratch-in-output: W bf16 packs live in logits+logprobs (overwritten by
  // row_logits AFTER the GEMM); psi packs live in probs (overwritten last).
  ushort* Wrh = (ushort*)logits;               // [32000][1024] each
  ushort* Wrl = Wrh + 32768000;
  ushort* Wih = (ushort*)logprobs;
  ushort* Wil = Wih + 32768000;
  ushort* APk = (ushort*)probs;                // [4][1024][1024]

  float* ws     = (float*)d_ws;
  float* ws_kth = ws;                // 1024
  float* ws_vb  = ws + 1024;         // 1024
  int*   ws_ib  = (int*)(ws + 2048); // 1024
  float* ws_mx  = ws + 3072;         // 1024
  float* ws_dk  = ws + 4096;         // 1024

  // pack psi (negated imag) and W into bf16 hi/lo
  pack_split<<<1024, 256, 0, stream>>>(pr, pi,
      APk, APk + (1 << 20), APk + (2 << 20), APk + (3 << 20), -1.0f, 262144);
  pack_split<<<32000, 256, 0, stream>>>(wr, wi,
      Wrh, Wrl, Wih, Wil, 1.0f, 8192000);

  gemm_mfma<<<2000, 512, 0, stream>>>(APk, Wrh, Wrl, Wih, Wil, ampsq);

  row_logits<<<BS, 256, 0, stream>>>(ampsq, bias, logits, logprobs);
  topk_sel<<<BS, 256, 0, stream>>>(logits, ws_kth);
  topp_sel<<<BS, 256, 0, stream>>>(logits, ws_kth, ws_vb, ws_ib, ws_mx, ws_dk);
  probs_tokens<<<BS, 256, 0, stream>>>(logits, ws_vb, ws_ib, ws_mx, ws_dk, probs, tokens);
}

// Round 7
// 1025.275 us; speedup vs baseline: 4.6971x; 1.3872x over previous
//
#include <hip/hip_runtime.h>

// Problem constants
#define BS   1024        // B*S rows
#define DD   1024        // D (= K)
#define VV   32000       // V
#define TOPK 50
#define TOPPF 0.95f
#define NVTOT 32768000ull   // BS*VV

typedef __attribute__((ext_vector_type(8))) short bf16x8;
typedef __attribute__((ext_vector_type(4))) float f32x4;
typedef __attribute__((ext_vector_type(4))) int   i32x4;

#define MFMA(A,B,C) __builtin_amdgcn_mfma_f32_16x16x32_bf16(A, B, C, 0, 0, 0)

// ---------------------------------------------------------------- utilities
__device__ __forceinline__ unsigned fkey(float f) {
  unsigned u = __float_as_uint(f);
  return (u & 0x80000000u) ? ~u : (u | 0x80000000u);
}
__device__ __forceinline__ unsigned rotl32(unsigned x, int r) {
  return (x << r) | (x >> (32 - r));
}
__device__ __forceinline__ ushort f2bf(float f) {   // fp32 -> bf16 RNE
  unsigned u = __float_as_uint(f);
  unsigned r = ((u >> 16) & 1u) + 0x7FFFu;
  return (ushort)((u + r) >> 16);
}
__device__ __forceinline__ float bf2f(ushort h) {
  return __uint_as_float(((unsigned)h) << 16);
}
__device__ __forceinline__ bf16x8 negbf(bf16x8 a) {  // flip sign of 8 bf16
  i32x4 t = __builtin_bit_cast(i32x4, a);
  t = t ^ 0x80008000;
  return __builtin_bit_cast(bf16x8, t);
}

// JAX threefry2x32-20, key=(0,42), partitionable: counter (0, i), bits = w0^w1.
__device__ float gumbel_at(unsigned i) {
  unsigned x0 = 0u, x1 = i;
  const unsigned ks0 = 0u, ks1 = 42u, ks2 = 0x1BD11BDAu ^ 0u ^ 42u;
  x0 += ks0; x1 += ks1;
  const int rotA[4] = {13, 15, 26, 6};
  const int rotB[4] = {17, 29, 16, 24};
#define TF_R4(R) { x0 += x1; x1 = rotl32(x1, R[0]); x1 ^= x0; \
                   x0 += x1; x1 = rotl32(x1, R[1]); x1 ^= x0; \
                   x0 += x1; x1 = rotl32(x1, R[2]); x1 ^= x0; \
                   x0 += x1; x1 = rotl32(x1, R[3]); x1 ^= x0; }
  TF_R4(rotA); x0 += ks1; x1 += ks2 + 1u;
  TF_R4(rotB); x0 += ks2; x1 += ks0 + 2u;
  TF_R4(rotA); x0 += ks0; x1 += ks1 + 3u;
  TF_R4(rotB); x0 += ks1; x1 += ks2 + 4u;
  TF_R4(rotA); x0 += ks2; x1 += ks0 + 5u;
#undef TF_R4
  unsigned bits = x0 ^ x1;
  float f = __uint_as_float(0x3F800000u | (bits >> 9)) - 1.0f;
  float u = fmaxf(f, 1.17549435e-38f);
  return -logf(-logf(u));
}

// ------------------------------------------------- split fp32 -> bf16 hi/lo
__global__ __launch_bounds__(256) void pack_split(
    const float* __restrict__ xr, const float* __restrict__ xi,
    ushort* __restrict__ ohr, ushort* __restrict__ olr,
    ushort* __restrict__ ohi, ushort* __restrict__ oli,
    float si, int n4) {
  int g = blockIdx.x * 256 + threadIdx.x;
  if (g >= n4) return;
  int i = g * 4;
  float4 a = *(const float4*)(xr + i);
  float4 b = *(const float4*)(xi + i);
  float av[4] = {a.x, a.y, a.z, a.w};
  float bv[4] = {b.x * si, b.y * si, b.z * si, b.w * si};
  unsigned hr[4], lr[4], hi_[4], li[4];
#pragma unroll
  for (int j = 0; j < 4; ++j) {
    ushort h = f2bf(av[j]);          hr[j] = h;
    lr[j] = f2bf(av[j] - bf2f(h));
    ushort h2 = f2bf(bv[j]);         hi_[j] = h2;
    li[j] = f2bf(bv[j] - bf2f(h2));
  }
  uint2 w;
  w.x = hr[0] | (hr[1] << 16); w.y = hr[2] | (hr[3] << 16);
  *(uint2*)(ohr + i) = w;
  w.x = lr[0] | (lr[1] << 16); w.y = lr[2] | (lr[3] << 16);
  *(uint2*)(olr + i) = w;
  w.x = hi_[0] | (hi_[1] << 16); w.y = hi_[2] | (hi_[3] << 16);
  *(uint2*)(ohi + i) = w;
  w.x = li[0] | (li[1] << 16); w.y = li[2] | (li[3] << 16);
  *(uint2*)(oli + i) = w;
}

// ---------------------------------------------------------------- MFMA GEMM
// amp_sq = |(Pr + iPi) . (Wr + iWi)|^2, split-bf16 (3-term), 12 MFMA/frag-pair.
// Block 128x128, 8 waves (2x4), BK=32, DOUBLE-BUFFERED LDS (2-phase: stage
// next K-tile before computing current; single syncthreads per step drains).
// LDS slot swizzle: phys_slot = log_slot ^ (r&3) ^ ((r>>2)&3), applied
// inversely on the global source (global_load_lds writes linearly).
__global__ __launch_bounds__(512) void gemm_mfma(
    const ushort* __restrict__ APk,                      // [4][1024][1024]
    const ushort* __restrict__ Wrh, const ushort* __restrict__ Wrl,
    const ushort* __restrict__ Wih, const ushort* __restrict__ Wil,
    float* __restrict__ amp) {
  __shared__ ushort lds[2][8][4096];   // 2 bufs x 8 tiles x (128r x 32k) = 128KB
  const int tid = threadIdx.x;
  const int lane = tid & 63, wid = tid >> 6;
  const int bm = blockIdx.x & 7, bn = blockIdx.x >> 3;
  const int row0 = bm << 7, col0 = bn << 7;
  const int wm = wid >> 2, wn = wid & 3;     // wave grid 2(M) x 4(N)

  const ushort* tp[8] = {APk, APk + (1 << 20), APk + (2 << 20), APk + (3 << 20),
                         Wrh, Wrl, Wih, Wil};

  // staging addressing (per thread, step-invariant part)
  const int rrow = tid >> 2;                     // tile row 0..127
  const int ss = (tid & 3) ^ (rrow & 3) ^ ((rrow >> 2) & 3);  // src slot
  const size_t offA = (size_t)(row0 + rrow) * DD + (ss << 3);
  const size_t offB = (size_t)(col0 + rrow) * DD + (ss << 3);

  f32x4 accr[4][2] = {}, acci[4][2] = {};

  // compute-side LDS byte offsets (step-invariant)
  int aoff[4], boff[2];
#pragma unroll
  for (int m = 0; m < 4; ++m) {
    const int ar = (wm << 6) + (m << 4) + (lane & 15);
    aoff[m] = (ar << 6) + ((((lane >> 4)) ^ (ar & 3) ^ ((ar >> 2) & 3)) << 4);
  }
#pragma unroll
  for (int n = 0; n < 2; ++n) {
    const int br = (wn << 5) + (n << 4) + (lane & 15);
    boff[n] = (br << 6) + ((((lane >> 4)) ^ (br & 3) ^ ((br >> 2) & 3)) << 4);
  }

#define STAGE(buf, step) {                                                   \
    const int k0 = (step) << 5;                                              \
    _Pragma("unroll")                                                        \
    for (int t = 0; t < 8; ++t) {                                            \
      const ushort* src = tp[t] + ((t < 4) ? offA : offB) + k0;              \
      __builtin_amdgcn_global_load_lds(                                      \
          (const __attribute__((address_space(1))) unsigned int*)src,        \
          (__attribute__((address_space(3))) unsigned int*)&lds[buf][t][wid << 9], \
          16, 0, 0);                                                         \
    }                                                                        \
  }

  STAGE(0, 0);
  __syncthreads();
  int cur = 0;
  for (int step = 0; step < 32; ++step) {
    if (step + 1 < 32) STAGE(cur ^ 1, step + 1);
    const char* L0 = (const char*)&lds[cur][0][0];
    const char* L1 = (const char*)&lds[cur][1][0];
    const char* L2 = (const char*)&lds[cur][2][0];
    const char* L3 = (const char*)&lds[cur][3][0];
    const char* L4 = (const char*)&lds[cur][4][0];
    const char* L5 = (const char*)&lds[cur][5][0];
    const char* L6 = (const char*)&lds[cur][6][0];
    const char* L7 = (const char*)&lds[cur][7][0];
    bf16x8 aPrh[4], aPrl[4], aNih[4], aNil[4], aPih[4], aPil[4];
#pragma unroll
    for (int m = 0; m < 4; ++m) {
      aPrh[m] = *(const bf16x8*)(L0 + aoff[m]);
      aPrl[m] = *(const bf16x8*)(L1 + aoff[m]);
      aNih[m] = *(const bf16x8*)(L2 + aoff[m]);
      aNil[m] = *(const bf16x8*)(L3 + aoff[m]);
      aPih[m] = negbf(aNih[m]);
      aPil[m] = negbf(aNil[m]);
    }
#pragma unroll
    for (int n = 0; n < 2; ++n) {
      bf16x8 bRh = *(const bf16x8*)(L4 + boff[n]);
      bf16x8 bRl = *(const bf16x8*)(L5 + boff[n]);
      bf16x8 bIh = *(const bf16x8*)(L6 + boff[n]);
      bf16x8 bIl = *(const bf16x8*)(L7 + boff[n]);
#pragma unroll
      for (int m = 0; m < 4; ++m) {
        f32x4 r = accr[m][n], q = acci[m][n];
        r = MFMA(aPrh[m], bRh, r); r = MFMA(aPrh[m], bRl, r); r = MFMA(aPrl[m], bRh, r);
        r = MFMA(aNih[m], bIh, r); r = MFMA(aNih[m], bIl, r); r = MFMA(aNil[m], bIh, r);
        q = MFMA(aPih[m], bRh, q); q = MFMA(aPih[m], bRl, q); q = MFMA(aPil[m], bRh, q);
        q = MFMA(aPrh[m], bIh, q); q = MFMA(aPrh[m], bIl, q); q = MFMA(aPrl[m], bIh, q);
        accr[m][n] = r; acci[m][n] = q;
      }
    }
    __syncthreads();   // drains vmcnt(0): next buffer staged; all reads done
    cur ^= 1;
  }
#undef STAGE
  // epilogue: C/D mapping col=lane&15, row=(lane>>4)*4+reg
#pragma unroll
  for (int m = 0; m < 4; ++m)
#pragma unroll
    for (int n = 0; n < 2; ++n)
#pragma unroll
      for (int qi = 0; qi < 4; ++qi) {
        const int row = row0 + (wm << 6) + (m << 4) + ((lane >> 4) << 2) + qi;
        const int col = col0 + (wn << 5) + (n << 4) + (lane & 15);
        float vr = accr[m][n][qi], vi = acci[m][n][qi];
        amp[(size_t)row * VV + col] = vr * vr + vi * vi;
      }
}

// ---------------------------------------------------------- fused row post
// One block per row. amp row staged in LDS; logits/logprobs/probs written
// once; top-k via 12-bit histogram + survivor sort from LDS; gumbel tokens.
__global__ __launch_bounds__(512) void post_row(
    const float* __restrict__ amp, const float* __restrict__ bias,
    float* __restrict__ logits, float* __restrict__ logprobs,
    float* __restrict__ probs, float* __restrict__ tokens) {
  __shared__ __align__(16) float lg[VV];      // 128000 B
  __shared__ int hist[4096];                  // 16384 B
  __shared__ int iscan[512];                  // 2048 B
  __shared__ float red[512];                  // 2048 B
  __shared__ float sval[768]; __shared__ int sidx[768];
  __shared__ float ssv[768];  __shared__ int ssi[768];
  __shared__ int scnt;
  __shared__ float sh_f[4];   // 0:floorv 1:mx 2:dk 3:vb
  __shared__ int   sh_i[4];   // 0:chunk 1:bin 2:ib

  const int row = blockIdx.x, tid = threadIdx.x;
  const float* A = amp + (size_t)row * VV;
  float* Lg = logits + (size_t)row * VV;
  float* Lp = logprobs + (size_t)row * VV;
  float* P  = probs + (size_t)row * VV;

  // pass 1: load amp -> LDS, row sum
  float s = 0.f;
  for (int i = tid; i < VV / 4; i += 512) {
    float4 a = ((const float4*)A)[i];
    ((float4*)lg)[i] = a;
    s += a.x + a.y + a.z + a.w;
  }
  red[tid] = s; __syncthreads();
  for (int o = 256; o > 0; o >>= 1) { if (tid < o) red[tid] += red[tid + o]; __syncthreads(); }
  if (tid == 0) sh_f[0] = red[0] * (1.0f / (float)VV) * 1e-6f + 1e-30f;
  __syncthreads();
  const float floorv = sh_f[0];
  __syncthreads();

  // pass 2: logits = log(amp+floor)+bias; store LDS + global; track max
  float mx = -INFINITY;
  for (int i = tid; i < VV / 4; i += 512) {
    float4 a = ((float4*)lg)[i];
    float4 b = ((const float4*)bias)[i];
    float4 l;
    l.x = logf(a.x + floorv) + b.x;
    l.y = logf(a.y + floorv) + b.y;
    l.z = logf(a.z + floorv) + b.z;
    l.w = logf(a.w + floorv) + b.w;
    ((float4*)lg)[i] = l;
    ((float4*)Lg)[i] = l;
    mx = fmaxf(mx, fmaxf(fmaxf(l.x, l.y), fmaxf(l.z, l.w)));
  }
  red[tid] = mx; __syncthreads();
  for (int o = 256; o > 0; o >>= 1) { if (tid < o) red[tid] = fmaxf(red[tid], red[tid + o]); __syncthreads(); }
  mx = red[0]; __syncthreads();

  // pass 3: sumexp
  float se = 0.f;
  for (int i = tid; i < VV / 4; i += 512) {
    float4 l = ((float4*)lg)[i];
    se += expf(l.x - mx) + expf(l.y - mx) + expf(l.z - mx) + expf(l.w - mx);
  }
  red[tid] = se; __syncthreads();
  for (int o = 256; o > 0; o >>= 1) { if (tid < o) red[tid] += red[tid + o]; __syncthreads(); }
  const float lse = mx + logf(red[0]);
  __syncthreads();

  // pass 4: logprobs
  for (int i = tid; i < VV / 4; i += 512) {
    float4 l = ((float4*)lg)[i];
    float4 o4 = {l.x - lse, l.y - lse, l.z - lse, l.w - lse};
    ((float4*)Lp)[i] = o4;
  }

  // pass 5: 12-bit histogram of fkey(logits)
  for (int i = tid; i < 4096; i += 512) hist[i] = 0;
  if (tid == 0) scnt = 0;
  __syncthreads();
  for (int v = tid; v < VV; v += 512)
    atomicAdd(&hist[fkey(lg[v]) >> 20], 1);
  __syncthreads();
  // descending chunks of 8 bins; inclusive scan; find top-k crossing
  {
    const int hi = 4095 - 8 * tid;
    int part = 0;
#pragma unroll
    for (int j = 0; j < 8; ++j) part += hist[hi - j];
    iscan[tid] = part;
    __syncthreads();
    for (int off = 1; off < 512; off <<= 1) {
      int add = (tid >= off) ? iscan[tid - off] : 0;
      __syncthreads();
      iscan[tid] += add;
      __syncthreads();
    }
    int cum = iscan[tid], prev = tid ? iscan[tid - 1] : 0;
    if (cum >= TOPK && prev < TOPK) sh_i[0] = tid;
    __syncthreads();
    if (tid == 0) {
      int tc = sh_i[0];
      int c = tc ? iscan[tc - 1] : 0;
      int b = 4095 - 8 * tc;
      for (int j = 0; j < 8; ++j) {
        int h = hist[4095 - 8 * tc - j];
        if (c + h >= TOPK) { b = 4095 - 8 * tc - j; break; }
        c += h;
      }
      sh_i[1] = b;
    }
    __syncthreads();
  }
  const unsigned binb = (unsigned)sh_i[1];

  // gather survivors (all elems in bins >= binb; superset of top-k)
  for (int v = tid; v < VV; v += 512) {
    if ((fkey(lg[v]) >> 20) >= binb) {
      int p = atomicAdd(&scnt, 1);
      if (p < 768) { sval[p] = lg[v]; sidx[p] = v; }
    }
  }
  __syncthreads();
  const int n = min(scnt, 768);
  // rank sort: value desc, index asc
  for (int i = tid; i < n; i += 512) {
    float vi = sval[i]; int ii = sidx[i]; int r = 0;
    for (int j = 0; j < n; ++j) {
      float vj = sval[j]; int ij = sidx[j];
      r += (vj > vi) || (vj == vi && ij < ii);
    }
    ssv[r] = vi; ssi[r] = ii;
  }
  __syncthreads();
  if (tid == 0) {
    const float kthv = ssv[TOPK - 1];
    int np = TOPK;
    while (np < n && ssv[np] >= kthv) ++np;
    const float mx2 = ssv[0];
    float denom = 0.f;
    for (int j = 0; j < np; ++j) denom += expf(ssv[j] - mx2);
    float cum = 0.f; int m = np;
    for (int j = 0; j < np; ++j) {
      float sp = expf(ssv[j] - mx2) / denom;
      cum += sp;
      if (cum - sp >= TOPPF) { m = j; break; }
    }
    float dk = 0.f;
    for (int j = 0; j < m; ++j) dk += expf(ssv[j] - mx2);
    sh_f[1] = mx2; sh_f[2] = dk; sh_f[3] = ssv[m - 1];
    sh_i[2] = ssi[m - 1];
  }
  __syncthreads();
  const float mx2 = sh_f[1], dk = sh_f[2], vb = sh_f[3];
  const int ib = sh_i[2];

  // pass 6: probs + gumbel argmax
  float best = -INFINITY; int bidx = 0x7FFFFFFF;
  for (int i = tid; i < VV / 4; i += 512) {
    float4 l4 = ((float4*)lg)[i];
    float lv[4] = {l4.x, l4.y, l4.z, l4.w};
    float4 p4 = {0.f, 0.f, 0.f, 0.f};
    float pv[4] = {0.f, 0.f, 0.f, 0.f};
#pragma unroll
    for (int j = 0; j < 4; ++j) {
      const int v = i * 4 + j;
      float l = lv[j];
      bool kept = (l > vb) || (l == vb && v <= ib);
      if (kept) {
        pv[j] = expf(l - mx2) / dk;
        float g = gumbel_at((unsigned)(row * VV + v));
        float sc = l + g;
        if (sc > best || (sc == best && v < bidx)) { best = sc; bidx = v; }
      }
    }
    p4.x = pv[0]; p4.y = pv[1]; p4.z = pv[2]; p4.w = pv[3];
    ((float4*)P)[i] = p4;
  }
  red[tid] = best; iscan[tid] = bidx; __syncthreads();
  for (int o = 256; o > 0; o >>= 1) {
    if (tid < o) {
      if (red[tid + o] > red[tid] ||
          (red[tid + o] == red[tid] && iscan[tid + o] < iscan[tid])) {
        red[tid] = red[tid + o]; iscan[tid] = iscan[tid + o];
      }
    }
    __syncthreads();
  }
  if (tid == 0) tokens[row] = (float)iscan[0];
}

// ---------------------------------------------------------------- launcher
extern "C" void kernel_launch(void* const* d_in, const int* in_sizes, int n_in,
                              void* d_out, int out_size, void* d_ws, size_t ws_size,
                              hipStream_t stream) {
  const float* pr   = (const float*)d_in[0];
  const float* pi   = (const float*)d_in[1];
  const float* wr   = (const float*)d_in[2];
  const float* wi   = (const float*)d_in[3];
  const float* bias = (const float*)d_in[4];

  float* out      = (float*)d_out;
  float* logits   = out;                       // [1024, 32000]
  float* logprobs = out + NVTOT;               // [1024, 32000]
  float* ampsq    = out + 2 * NVTOT;           // [1024, 32000]
  float* tokens   = out + 3 * NVTOT;           // [1024]
  float* probs    = out + 3 * NVTOT + 1024;    // [1024, 32000]

  // scratch-in-output: W bf16 packs live in logits+logprobs (overwritten by
  // post_row AFTER the GEMM); psi packs live in probs (overwritten last).
  ushort* Wrh = (ushort*)logits;               // [32000][1024] each
  ushort* Wrl = Wrh + 32768000;
  ushort* Wih = (ushort*)logprobs;
  ushort* Wil = Wih + 32768000;
  ushort* APk = (ushort*)probs;                // [4][1024][1024]

  // pack psi (negated imag) and W into bf16 hi/lo
  pack_split<<<1024, 256, 0, stream>>>(pr, pi,
      APk, APk + (1 << 20), APk + (2 << 20), APk + (3 << 20), -1.0f, 262144);
  pack_split<<<32000, 256, 0, stream>>>(wr, wi,
      Wrh, Wrl, Wih, Wil, 1.0f, 8192000);

  gemm_mfma<<<2000, 512, 0, stream>>>(APk, Wrh, Wrl, Wih, Wil, ampsq);

  post_row<<<BS, 512, 0, stream>>>(ampsq, bias, logits, logprobs, probs, tokens);
}

// Round 8
// 999.960 us; speedup vs baseline: 4.8160x; 1.0253x over previous
//
#include <hip/hip_runtime.h>

// Problem constants
#define BS   1024        // B*S rows
#define DD   1024        // D (= K)
#define VV   32000       // V
#define TOPK 50
#define TOPPF 0.95f
#define NVTOT 32768000ull   // BS*VV

typedef __attribute__((ext_vector_type(8))) short bf16x8;
typedef __attribute__((ext_vector_type(4))) float f32x4;
typedef __attribute__((ext_vector_type(4))) int   i32x4;

#define MFMA(A,B,C) __builtin_amdgcn_mfma_f32_16x16x32_bf16(A, B, C, 0, 0, 0)

// ---------------------------------------------------------------- utilities
__device__ __forceinline__ unsigned fkey(float f) {
  unsigned u = __float_as_uint(f);
  return (u & 0x80000000u) ? ~u : (u | 0x80000000u);
}
__device__ __forceinline__ unsigned rotl32(unsigned x, int r) {
  return (x << r) | (x >> (32 - r));
}
__device__ __forceinline__ ushort f2bf(float f) {   // fp32 -> bf16 RNE
  unsigned u = __float_as_uint(f);
  unsigned r = ((u >> 16) & 1u) + 0x7FFFu;
  return (ushort)((u + r) >> 16);
}
__device__ __forceinline__ float bf2f(ushort h) {
  return __uint_as_float(((unsigned)h) << 16);
}
__device__ __forceinline__ bf16x8 negbf(bf16x8 a) {  // flip sign of 8 bf16
  i32x4 t = __builtin_bit_cast(i32x4, a);
  t = t ^ 0x80008000;
  return __builtin_bit_cast(bf16x8, t);
}

// JAX threefry2x32-20, key=(0,42), partitionable: counter (0, i), bits = w0^w1.
__device__ float gumbel_at(unsigned i) {
  unsigned x0 = 0u, x1 = i;
  const unsigned ks0 = 0u, ks1 = 42u, ks2 = 0x1BD11BDAu ^ 0u ^ 42u;
  x0 += ks0; x1 += ks1;
  const int rotA[4] = {13, 15, 26, 6};
  const int rotB[4] = {17, 29, 16, 24};
#define TF_R4(R) { x0 += x1; x1 = rotl32(x1, R[0]); x1 ^= x0; \
                   x0 += x1; x1 = rotl32(x1, R[1]); x1 ^= x0; \
                   x0 += x1; x1 = rotl32(x1, R[2]); x1 ^= x0; \
                   x0 += x1; x1 = rotl32(x1, R[3]); x1 ^= x0; }
  TF_R4(rotA); x0 += ks1; x1 += ks2 + 1u;
  TF_R4(rotB); x0 += ks2; x1 += ks0 + 2u;
  TF_R4(rotA); x0 += ks0; x1 += ks1 + 3u;
  TF_R4(rotB); x0 += ks1; x1 += ks2 + 4u;
  TF_R4(rotA); x0 += ks2; x1 += ks0 + 5u;
#undef TF_R4
  unsigned bits = x0 ^ x1;
  float f = __uint_as_float(0x3F800000u | (bits >> 9)) - 1.0f;
  float u = fmaxf(f, 1.17549435e-38f);
  return -logf(-logf(u));
}

// ------------------------------------------------- split fp32 -> bf16 hi/lo
__global__ __launch_bounds__(256) void pack_split(
    const float* __restrict__ xr, const float* __restrict__ xi,
    ushort* __restrict__ ohr, ushort* __restrict__ olr,
    ushort* __restrict__ ohi, ushort* __restrict__ oli,
    float si, int n4) {
  int g = blockIdx.x * 256 + threadIdx.x;
  if (g >= n4) return;
  int i = g * 4;
  float4 a = *(const float4*)(xr + i);
  float4 b = *(const float4*)(xi + i);
  float av[4] = {a.x, a.y, a.z, a.w};
  float bv[4] = {b.x * si, b.y * si, b.z * si, b.w * si};
  unsigned hr[4], lr[4], hi_[4], li[4];
#pragma unroll
  for (int j = 0; j < 4; ++j) {
    ushort h = f2bf(av[j]);          hr[j] = h;
    lr[j] = f2bf(av[j] - bf2f(h));
    ushort h2 = f2bf(bv[j]);         hi_[j] = h2;
    li[j] = f2bf(bv[j] - bf2f(h2));
  }
  uint2 w;
  w.x = hr[0] | (hr[1] << 16); w.y = hr[2] | (hr[3] << 16);
  *(uint2*)(ohr + i) = w;
  w.x = lr[0] | (lr[1] << 16); w.y = lr[2] | (lr[3] << 16);
  *(uint2*)(olr + i) = w;
  w.x = hi_[0] | (hi_[1] << 16); w.y = hi_[2] | (hi_[3] << 16);
  *(uint2*)(ohi + i) = w;
  w.x = li[0] | (li[1] << 16); w.y = li[2] | (li[3] << 16);
  *(uint2*)(oli + i) = w;
}

// ---------------------------------------------------------------- MFMA GEMM
// amp_sq = |(Pr + iPi) . (Wr + iWi)|^2, split-bf16 (3-term), 12 MFMA/frag-pair.
// Block 128x128, 8 waves (2x4), BK=32, double-buffered LDS, 2-phase.
// XCD-partition remap: xcd x = bid&7 owns bm-pair (x>>1) and bn-half (x&1);
// within an XCD, bn walks with bm alternating innermost -> A packs (2MB)
// L2-resident per XCD; B panels streamed ~once.
__global__ __launch_bounds__(512) void gemm_mfma(
    const ushort* __restrict__ APk,                      // [4][1024][1024]
    const ushort* __restrict__ Wrh, const ushort* __restrict__ Wrl,
    const ushort* __restrict__ Wih, const ushort* __restrict__ Wil,
    float* __restrict__ amp) {
  __shared__ ushort lds[2][8][4096];   // 2 bufs x 8 tiles x (128r x 32k) = 128KB
  const int tid = threadIdx.x;
  const int lane = tid & 63, wid = tid >> 6;
  const int d = blockIdx.x;
  const int x = d & 7, s = d >> 3;
  const int bm = ((x >> 1) << 1) | (s & 1);       // bm-pair per XCD
  const int bn = (x & 1) * 125 + (s >> 1);        // bn-half per XCD
  const int row0 = bm << 7, col0 = bn << 7;
  const int wm = wid >> 2, wn = wid & 3;     // wave grid 2(M) x 4(N)

  const ushort* tp[8] = {APk, APk + (1 << 20), APk + (2 << 20), APk + (3 << 20),
                         Wrh, Wrl, Wih, Wil};

  // staging addressing (per thread, step-invariant part)
  const int rrow = tid >> 2;                     // tile row 0..127
  const int ss = (tid & 3) ^ (rrow & 3) ^ ((rrow >> 2) & 3);  // src slot
  const size_t offA = (size_t)(row0 + rrow) * DD + (ss << 3);
  const size_t offB = (size_t)(col0 + rrow) * DD + (ss << 3);

  f32x4 accr[4][2] = {}, acci[4][2] = {};

  // compute-side LDS byte offsets (step-invariant)
  int aoff[4], boff[2];
#pragma unroll
  for (int m = 0; m < 4; ++m) {
    const int ar = (wm << 6) + (m << 4) + (lane & 15);
    aoff[m] = (ar << 6) + ((((lane >> 4)) ^ (ar & 3) ^ ((ar >> 2) & 3)) << 4);
  }
#pragma unroll
  for (int n = 0; n < 2; ++n) {
    const int br = (wn << 5) + (n << 4) + (lane & 15);
    boff[n] = (br << 6) + ((((lane >> 4)) ^ (br & 3) ^ ((br >> 2) & 3)) << 4);
  }

#define STAGE(buf, step) {                                                   \
    const int k0 = (step) << 5;                                              \
    _Pragma("unroll")                                                        \
    for (int t = 0; t < 8; ++t) {                                            \
      const ushort* src = tp[t] + ((t < 4) ? offA : offB) + k0;              \
      __builtin_amdgcn_global_load_lds(                                      \
          (const __attribute__((address_space(1))) unsigned int*)src,        \
          (__attribute__((address_space(3))) unsigned int*)&lds[buf][t][wid << 9], \
          16, 0, 0);                                                         \
    }                                                                        \
  }

  STAGE(0, 0);
  __syncthreads();
  int cur = 0;
  for (int step = 0; step < 32; ++step) {
    if (step + 1 < 32) STAGE(cur ^ 1, step + 1);
    const char* L0 = (const char*)&lds[cur][0][0];
    const char* L1 = (const char*)&lds[cur][1][0];
    const char* L2 = (const char*)&lds[cur][2][0];
    const char* L3 = (const char*)&lds[cur][3][0];
    const char* L4 = (const char*)&lds[cur][4][0];
    const char* L5 = (const char*)&lds[cur][5][0];
    const char* L6 = (const char*)&lds[cur][6][0];
    const char* L7 = (const char*)&lds[cur][7][0];
    bf16x8 aPrh[4], aPrl[4], aNih[4], aNil[4], aPih[4], aPil[4];
#pragma unroll
    for (int m = 0; m < 4; ++m) {
      aPrh[m] = *(const bf16x8*)(L0 + aoff[m]);
      aPrl[m] = *(const bf16x8*)(L1 + aoff[m]);
      aNih[m] = *(const bf16x8*)(L2 + aoff[m]);
      aNil[m] = *(const bf16x8*)(L3 + aoff[m]);
      aPih[m] = negbf(aNih[m]);
      aPil[m] = negbf(aNil[m]);
    }
#pragma unroll
    for (int n = 0; n < 2; ++n) {
      bf16x8 bRh = *(const bf16x8*)(L4 + boff[n]);
      bf16x8 bRl = *(const bf16x8*)(L5 + boff[n]);
      bf16x8 bIh = *(const bf16x8*)(L6 + boff[n]);
      bf16x8 bIl = *(const bf16x8*)(L7 + boff[n]);
#pragma unroll
      for (int m = 0; m < 4; ++m) {
        f32x4 r = accr[m][n], q = acci[m][n];
        r = MFMA(aPrh[m], bRh, r); r = MFMA(aPrh[m], bRl, r); r = MFMA(aPrl[m], bRh, r);
        r = MFMA(aNih[m], bIh, r); r = MFMA(aNih[m], bIl, r); r = MFMA(aNil[m], bIh, r);
        q = MFMA(aPih[m], bRh, q); q = MFMA(aPih[m], bRl, q); q = MFMA(aPil[m], bRh, q);
        q = MFMA(aPrh[m], bIh, q); q = MFMA(aPrh[m], bIl, q); q = MFMA(aPrl[m], bIh, q);
        accr[m][n] = r; acci[m][n] = q;
      }
    }
    __syncthreads();   // drains vmcnt(0): next buffer staged; all reads done
    cur ^= 1;
  }
#undef STAGE
  // epilogue: C/D mapping col=lane&15, row=(lane>>4)*4+reg
#pragma unroll
  for (int m = 0; m < 4; ++m)
#pragma unroll
    for (int n = 0; n < 2; ++n)
#pragma unroll
      for (int qi = 0; qi < 4; ++qi) {
        const int row = row0 + (wm << 6) + (m << 4) + ((lane >> 4) << 2) + qi;
        const int col = col0 + (wn << 5) + (n << 4) + (lane & 15);
        float vr = accr[m][n][qi], vi = acci[m][n][qi];
        amp[(size_t)row * VV + col] = vr * vr + vi * vi;
      }
}

// ---------------------------------------------------------- fused row post
__global__ __launch_bounds__(512) void post_row(
    const float* __restrict__ amp, const float* __restrict__ bias,
    float* __restrict__ logits, float* __restrict__ logprobs,
    float* __restrict__ probs, float* __restrict__ tokens) {
  __shared__ __align__(16) float lg[VV];      // 128000 B
  __shared__ int hist[4096];                  // 16384 B
  __shared__ int iscan[512];                  // 2048 B
  __shared__ float red[512];                  // 2048 B
  __shared__ float sval[768]; __shared__ int sidx[768];
  __shared__ float ssv[768];  __shared__ int ssi[768];
  __shared__ int scnt;
  __shared__ float sh_f[4];   // 0:floorv 1:mx 2:dk 3:vb
  __shared__ int   sh_i[4];   // 0:chunk 1:bin 2:ib

  const int row = blockIdx.x, tid = threadIdx.x;
  const float* A = amp + (size_t)row * VV;
  float* Lg = logits + (size_t)row * VV;
  float* Lp = logprobs + (size_t)row * VV;
  float* P  = probs + (size_t)row * VV;

  // pass 1: load amp -> LDS, row sum
  float s = 0.f;
  for (int i = tid; i < VV / 4; i += 512) {
    float4 a = ((const float4*)A)[i];
    ((float4*)lg)[i] = a;
    s += a.x + a.y + a.z + a.w;
  }
  red[tid] = s; __syncthreads();
  for (int o = 256; o > 0; o >>= 1) { if (tid < o) red[tid] += red[tid + o]; __syncthreads(); }
  if (tid == 0) sh_f[0] = red[0] * (1.0f / (float)VV) * 1e-6f + 1e-30f;
  __syncthreads();
  const float floorv = sh_f[0];
  __syncthreads();

  // pass 2: logits = log(amp+floor)+bias; store LDS + global; track max
  float mx = -INFINITY;
  for (int i = tid; i < VV / 4; i += 512) {
    float4 a = ((float4*)lg)[i];
    float4 b = ((const float4*)bias)[i];
    float4 l;
    l.x = logf(a.x + floorv) + b.x;
    l.y = logf(a.y + floorv) + b.y;
    l.z = logf(a.z + floorv) + b.z;
    l.w = logf(a.w + floorv) + b.w;
    ((float4*)lg)[i] = l;
    ((float4*)Lg)[i] = l;
    mx = fmaxf(mx, fmaxf(fmaxf(l.x, l.y), fmaxf(l.z, l.w)));
  }
  red[tid] = mx; __syncthreads();
  for (int o = 256; o > 0; o >>= 1) { if (tid < o) red[tid] = fmaxf(red[tid], red[tid + o]); __syncthreads(); }
  mx = red[0]; __syncthreads();

  // pass 3: sumexp
  float se = 0.f;
  for (int i = tid; i < VV / 4; i += 512) {
    float4 l = ((float4*)lg)[i];
    se += expf(l.x - mx) + expf(l.y - mx) + expf(l.z - mx) + expf(l.w - mx);
  }
  red[tid] = se; __syncthreads();
  for (int o = 256; o > 0; o >>= 1) { if (tid < o) red[tid] += red[tid + o]; __syncthreads(); }
  const float lse = mx + logf(red[0]);
  __syncthreads();

  // pass 4: logprobs
  for (int i = tid; i < VV / 4; i += 512) {
    float4 l = ((float4*)lg)[i];
    float4 o4 = {l.x - lse, l.y - lse, l.z - lse, l.w - lse};
    ((float4*)Lp)[i] = o4;
  }

  // pass 5: 12-bit histogram of fkey(logits)
  for (int i = tid; i < 4096; i += 512) hist[i] = 0;
  if (tid == 0) scnt = 0;
  __syncthreads();
  for (int v = tid; v < VV; v += 512)
    atomicAdd(&hist[fkey(lg[v]) >> 20], 1);
  __syncthreads();
  {
    const int hi = 4095 - 8 * tid;
    int part = 0;
#pragma unroll
    for (int j = 0; j < 8; ++j) part += hist[hi - j];
    iscan[tid] = part;
    __syncthreads();
    for (int off = 1; off < 512; off <<= 1) {
      int add = (tid >= off) ? iscan[tid - off] : 0;
      __syncthreads();
      iscan[tid] += add;
      __syncthreads();
    }
    int cum = iscan[tid], prev = tid ? iscan[tid - 1] : 0;
    if (cum >= TOPK && prev < TOPK) sh_i[0] = tid;
    __syncthreads();
    if (tid == 0) {
      int tc = sh_i[0];
      int c = tc ? iscan[tc - 1] : 0;
      int b = 4095 - 8 * tc;
      for (int j = 0; j < 8; ++j) {
        int h = hist[4095 - 8 * tc - j];
        if (c + h >= TOPK) { b = 4095 - 8 * tc - j; break; }
        c += h;
      }
      sh_i[1] = b;
    }
    __syncthreads();
  }
  const unsigned binb = (unsigned)sh_i[1];

  // gather survivors (all elems in bins >= binb; superset of top-k)
  for (int v = tid; v < VV; v += 512) {
    if ((fkey(lg[v]) >> 20) >= binb) {
      int p = atomicAdd(&scnt, 1);
      if (p < 768) { sval[p] = lg[v]; sidx[p] = v; }
    }
  }
  __syncthreads();
  const int n = min(scnt, 768);
  // rank sort: value desc, index asc
  for (int i = tid; i < n; i += 512) {
    float vi = sval[i]; int ii = sidx[i]; int r = 0;
    for (int j = 0; j < n; ++j) {
      float vj = sval[j]; int ij = sidx[j];
      r += (vj > vi) || (vj == vi && ij < ii);
    }
    ssv[r] = vi; ssi[r] = ii;
  }
  __syncthreads();
  if (tid == 0) {
    const float kthv = ssv[TOPK - 1];
    int np = TOPK;
    while (np < n && ssv[np] >= kthv) ++np;
    const float mx2 = ssv[0];
    float denom = 0.f;
    for (int j = 0; j < np; ++j) denom += expf(ssv[j] - mx2);
    float cum = 0.f; int m = np;
    for (int j = 0; j < np; ++j) {
      float sp = expf(ssv[j] - mx2) / denom;
      cum += sp;
      if (cum - sp >= TOPPF) { m = j; break; }
    }
    float dk = 0.f;
    for (int j = 0; j < m; ++j) dk += expf(ssv[j] - mx2);
    sh_f[1] = mx2; sh_f[2] = dk; sh_f[3] = ssv[m - 1];
    sh_i[2] = ssi[m - 1];
  }
  __syncthreads();
  const float mx2 = sh_f[1], dk = sh_f[2], vb = sh_f[3];
  const int ib = sh_i[2];

  // pass 6: probs + gumbel argmax
  float best = -INFINITY; int bidx = 0x7FFFFFFF;
  for (int i = tid; i < VV / 4; i += 512) {
    float4 l4 = ((float4*)lg)[i];
    float lv[4] = {l4.x, l4.y, l4.z, l4.w};
    float4 p4 = {0.f, 0.f, 0.f, 0.f};
    float pv[4] = {0.f, 0.f, 0.f, 0.f};
#pragma unroll
    for (int j = 0; j < 4; ++j) {
      const int v = i * 4 + j;
      float l = lv[j];
      bool kept = (l > vb) || (l == vb && v <= ib);
      if (kept) {
        pv[j] = expf(l - mx2) / dk;
        float g = gumbel_at((unsigned)(row * VV + v));
        float sc = l + g;
        if (sc > best || (sc == best && v < bidx)) { best = sc; bidx = v; }
      }
    }
    p4.x = pv[0]; p4.y = pv[1]; p4.z = pv[2]; p4.w = pv[3];
    ((float4*)P)[i] = p4;
  }
  red[tid] = best; iscan[tid] = bidx; __syncthreads();
  for (int o = 256; o > 0; o >>= 1) {
    if (tid < o) {
      if (red[tid + o] > red[tid] ||
          (red[tid + o] == red[tid] && iscan[tid + o] < iscan[tid])) {
        red[tid] = red[tid + o]; iscan[tid] = iscan[tid + o];
      }
    }
    __syncthreads();
  }
  if (tid == 0) tokens[row] = (float)iscan[0];
}

// ---------------------------------------------------------------- launcher
extern "C" void kernel_launch(void* const* d_in, const int* in_sizes, int n_in,
                              void* d_out, int out_size, void* d_ws, size_t ws_size,
                              hipStream_t stream) {
  const float* pr   = (const float*)d_in[0];
  const float* pi   = (const float*)d_in[1];
  const float* wr   = (const float*)d_in[2];
  const float* wi   = (const float*)d_in[3];
  const float* bias = (const float*)d_in[4];

  float* out      = (float*)d_out;
  float* logits   = out;                       // [1024, 32000]
  float* logprobs = out + NVTOT;               // [1024, 32000]
  float* ampsq    = out + 2 * NVTOT;           // [1024, 32000]
  float* tokens   = out + 3 * NVTOT;           // [1024]
  float* probs    = out + 3 * NVTOT + 1024;    // [1024, 32000]

  // scratch-in-output: W bf16 packs live in logits+logprobs (overwritten by
  // post_row AFTER the GEMM); psi packs live in probs (overwritten last).
  ushort* Wrh = (ushort*)logits;               // [32000][1024] each
  ushort* Wrl = Wrh + 32768000;
  ushort* Wih = (ushort*)logprobs;
  ushort* Wil = Wih + 32768000;
  ushort* APk = (ushort*)probs;                // [4][1024][1024]

  // pack psi (negated imag) and W into bf16 hi/lo
  pack_split<<<1024, 256, 0, stream>>>(pr, pi,
      APk, APk + (1 << 20), APk + (2 << 20), APk + (3 << 20), -1.0f, 262144);
  pack_split<<<32000, 256, 0, stream>>>(wr, wi,
      Wrh, Wrl, Wih, Wil, 1.0f, 8192000);

  gemm_mfma<<<2000, 512, 0, stream>>>(APk, Wrh, Wrl, Wih, Wil, ampsq);

  post_row<<<BS, 512, 0, stream>>>(ampsq, bias, logits, logprobs, probs, tokens);
}